// Round 10
// baseline (40.873 us; speedup 1.0000x reference)
//
#include <hip/hip_runtime.h>
#include <math.h>

#define TWO_PI_F 6.28318530717958647692f

typedef unsigned int u32;
typedef __attribute__((ext_vector_type(4))) u32      u32x4;
typedef __attribute__((ext_vector_type(4))) float    f4;
typedef __attribute__((ext_vector_type(2))) float    f2;
typedef __attribute__((ext_vector_type(2))) _Float16 h2;

union V8 { u32x4 v; h2 h[4]; };

#if __has_builtin(__builtin_amdgcn_fdot2)
#define FDOT2(a, b, c) __builtin_amdgcn_fdot2((a), (b), (c), false)
#else
__device__ __forceinline__ float FDOT2(h2 a, h2 b, float c) {
    return c + (float)a[0] * (float)b[0] + (float)a[1] * (float)b[1];
}
#endif

// ---------------------------------------------------------------------------
// Fused kernel: 32x32 output tile per block, upper-triangular blocks only
// (2080 blocks). ONE wave (64 threads) per block, each thread owns a 4x4
// patch -> 19 ds_read_b128 per 16 cells per h-group (LDS pipe decontended;
// VALU-bound with 16 independent f32 accumulators of ILP). Accumulation via
// v_dot2_f32_f16. A/B projections regenerated in-LDS; XOR-swizzled layout
// keeps all hot LDS ops broadcast/conflict-free with zero per-read addr math.
// ---------------------------------------------------------------------------
__global__ __launch_bounds__(64) void gd_fused(
    const float* __restrict__ z,  const float* __restrict__ s,
    const float* __restrict__ W1, const float* __restrict__ b1,
    const float* __restrict__ W2, const float* __restrict__ b2v,
    float* __restrict__ out, int N, int NB)
{
    __shared__ __attribute__((aligned(16))) _Float16 sAB[4][32][64]; // Ai,Bi,Aj,Bj
    __shared__ __attribute__((aligned(16))) _Float16 sWc[64], sWs[64], sW2[64];
    __shared__ __attribute__((aligned(16))) f4 strig2[64]; // {c1,s1,c2,s2}; 0:31=i, 32:63=j
    __shared__ float zc[64];

    // --- triangular block decode: u -> (bi, bj), bj >= bi ---
    int u = blockIdx.x;
    int M = 2 * NB + 1;
    float disc = (float)(M * M - 8 * u);
    int bi = (int)(((float)M - sqrtf(disc)) * 0.5f);
    if (bi < 0) bi = 0;
    if (bi > NB - 1) bi = NB - 1;
    while (bi > 0 && bi * (M - bi) / 2 > u) --bi;
    while ((bi + 1) * (M - (bi + 1)) / 2 <= u) ++bi;
    int bj = bi + (u - bi * (M - bi) / 2);

    int t = threadIdx.x;   // 0..63

    // --- setup: each thread does trig(row t) + zc[t] + weights[t] ---
    {
        int grow = (t < 32) ? (bi * 32 + t) : (bj * 32 + (t - 32));
        float ang = TWO_PI_F * s[grow];
        float c1 = __cosf(ang);
        float s1 = __sinf(ang);
        strig2[t] = (f4){c1, s1, c1 * c1 - s1 * s1, 2.0f * c1 * s1};
        float acc = b1[t];
#pragma unroll
        for (int zz = 0; zz < 32; ++zz)
            acc = fmaf(z[zz], W1[(10 + zz) * 64 + t], acc);
        zc[t] = acc;
        sWc[t] = (_Float16)W1[8 * 64 + t];
        sWs[t] = (_Float16)W1[9 * 64 + t];
        sW2[t] = (_Float16)(0.5f * W2[t]);   // fold 0.5 symmetrization
    }
    __syncthreads();

    // --- phase 1: generate A/B pairs (2 h per thread, 32 rows each) ---
    {
        int q  = t & 31;          // h-pair index: h = 2q, 2q+1
        int rg = t >> 5;          // 2 row-groups x 32 rows
        const f2* W1p = (const f2*)W1;
        f2 wv[8];
#pragma unroll
        for (int w = 0; w < 8; ++w) wv[w] = W1p[w * 32 + q];
        f2 zv = *(const f2*)&zc[2 * q];
#pragma unroll
        for (int rr = 0; rr < 32; ++rr) {
            int row = rg * 32 + rr;           // 0..63
            f4 tg = strig2[row];
            float A0 = zv.x, A1 = zv.y;
            A0 = fmaf(tg.x, wv[0].x, A0); A1 = fmaf(tg.x, wv[0].y, A1);
            A0 = fmaf(tg.y, wv[1].x, A0); A1 = fmaf(tg.y, wv[1].y, A1);
            A0 = fmaf(tg.z, wv[2].x, A0); A1 = fmaf(tg.z, wv[2].y, A1);
            A0 = fmaf(tg.w, wv[3].x, A0); A1 = fmaf(tg.w, wv[3].y, A1);
            float B0 = tg.x * wv[4].x, B1 = tg.x * wv[4].y;
            B0 = fmaf(tg.y, wv[5].x, B0); B1 = fmaf(tg.y, wv[5].y, B1);
            B0 = fmaf(tg.z, wv[6].x, B0); B1 = fmaf(tg.z, wv[6].y, B1);
            B0 = fmaf(tg.w, wv[7].x, B0); B1 = fmaf(tg.w, wv[7].y, B1);
            int arr = (row >> 5) * 2;         // 0: i-rows, 2: j-rows
            int lr  = row & 31;
            int colq = q ^ (((lr >> 2) & 7) << 2);   // pair-unit swizzle
            h2 Aw = {(_Float16)A0, (_Float16)A1};
            h2 Bw = {(_Float16)B0, (_Float16)B1};
            *(h2*)&sAB[arr + 0][lr][2 * colq] = Aw;
            *(h2*)&sAB[arr + 1][lr][2 * colq] = Bw;
        }
    }
    __syncthreads();

    // --- phase 2: 4x4 patch per thread ---
    int tj = t & 7;     // col quad: jl = tj*4 + c
    int ti = t >> 3;    // row quad: il = ti*4 + r

    int RK = (ti & 7) << 3;   // (il>>2)==ti for all 4 rows of the quad
    int CK = (tj & 7) << 3;

    h2 ct2[4][4], st2[4][4];
#pragma unroll
    for (int r = 0; r < 4; ++r) {
        int il = ti * 4 + r;
        f4 tgi = strig2[il];
#pragma unroll
        for (int c = 0; c < 4; ++c) {
            int jl = tj * 4 + c;
            f4 tgj = strig2[32 + jl];
            float cv = fmaf(tgi.x, tgj.x, tgi.y * tgj.y);            // cos(2pi*dist)
            float sv = fabsf(fmaf(tgi.y, tgj.x, -(tgi.x * tgj.y)));  // sin(2pi*dist)
            _Float16 cth = (_Float16)cv;
            _Float16 sth = (_Float16)sv;
            ct2[r][c] = (h2){cth, cth};
            st2[r][c] = (h2){sth, sth};
        }
    }

    float acc[4][4];
#pragma unroll
    for (int r = 0; r < 4; ++r)
#pragma unroll
        for (int c = 0; c < 4; ++c) acc[r][c] = 0.0f;

    int rbase[4], cbase[4];
#pragma unroll
    for (int r = 0; r < 4; ++r) rbase[r] = (ti * 4 + r) * 64;
#pragma unroll
    for (int c = 0; c < 4; ++c) cbase[c] = (tj * 4 + c) * 64;

    const _Float16* pAi = &sAB[0][0][0];
    const _Float16* pBi = &sAB[1][0][0];
    const _Float16* pAj = &sAB[2][0][0];
    const _Float16* pBj = &sAB[3][0][0];

#pragma unroll
    for (int hg = 0; hg < 8; ++hg) {
        const int h0 = hg * 8;
        V8 wc8, ws8, w28;
        wc8.v = *(const u32x4*)&sWc[h0];        // uniform addr -> broadcast
        ws8.v = *(const u32x4*)&sWs[h0];
        w28.v = *(const u32x4*)&sW2[h0];

        const int oR = h0 ^ RK;
        const int oC = h0 ^ CK;

        V8 ai8[4], bi8[4], aj8[4], bj8[4];
#pragma unroll
        for (int r = 0; r < 4; ++r) {
            ai8[r].v = *(const u32x4*)&pAi[rbase[r] + oR];
            bi8[r].v = *(const u32x4*)&pBi[rbase[r] + oR];
        }
#pragma unroll
        for (int c = 0; c < 4; ++c) {
            aj8[c].v = *(const u32x4*)&pAj[cbase[c] + oC];
            bj8[c].v = *(const u32x4*)&pBj[cbase[c] + oC];
        }

#pragma unroll
        for (int r = 0; r < 4; ++r) {
#pragma unroll
            for (int c = 0; c < 4; ++c) {
                h2 ct = ct2[r][c];
                h2 st = st2[r][c];
#pragma unroll
                for (int k = 0; k < 4; ++k) {
                    h2 d2 = __builtin_elementwise_fma(ct, wc8.h[k], st * ws8.h[k]);
                    h2 p1 = ai8[r].h[k] + bj8[c].h[k] + d2;   // (i,j)
                    h2 p2 = aj8[c].h[k] + bi8[r].h[k] + d2;   // (j,i)
                    h2 m  = __builtin_elementwise_max(p1, (h2)0) +
                            __builtin_elementwise_max(p2, (h2)0);
                    acc[r][c] = FDOT2(m, w28.h[k], acc[r][c]);
                }
            }
        }
    }

    float b2 = b2v[0];
    float vals[4][4];
#pragma unroll
    for (int r = 0; r < 4; ++r) {
        int gi = bi * 32 + ti * 4 + r;
#pragma unroll
        for (int c = 0; c < 4; ++c) {
            int gj = bj * 32 + tj * 4 + c;
            float v = acc[r][c] + b2;
            if (gi == gj) v = -1e9f;
            vals[r][c] = v;
        }
    }

    // direct (upper) tile: one float4 store per row
#pragma unroll
    for (int r = 0; r < 4; ++r) {
        int gi = bi * 32 + ti * 4 + r;
        f4 o = {vals[r][0], vals[r][1], vals[r][2], vals[r][3]};
        *(f4*)&out[(size_t)gi * N + bj * 32 + tj * 4] = o;
    }

    if (bj > bi) {   // mirrored block via LDS transpose (stride 33)
        __syncthreads();
        float* tile = (float*)&sAB[0][0][0];   // 32*33*4 = 4.2 KB inside sAB
#pragma unroll
        for (int r = 0; r < 4; ++r)
#pragma unroll
            for (int c = 0; c < 4; ++c)
                tile[(ti * 4 + r) * 33 + tj * 4 + c] = vals[r][c];
        __syncthreads();
#pragma unroll
        for (int r = 0; r < 4; ++r) {
            int orow = ti * 4 + r;             // j-space row
            f4 m;
#pragma unroll
            for (int c = 0; c < 4; ++c)
                m[c] = tile[(tj * 4 + c) * 33 + orow];
            *(f4*)&out[(size_t)(bj * 32 + orow) * N + bi * 32 + tj * 4] = m;
        }
    }
}

extern "C" void kernel_launch(void* const* d_in, const int* in_sizes, int n_in,
                              void* d_out, int out_size, void* d_ws, size_t ws_size,
                              hipStream_t stream) {
    const float* z  = (const float*)d_in[0];  // [32]
    const float* s  = (const float*)d_in[1];  // [N]
    const float* W1 = (const float*)d_in[2];  // [42,64]
    const float* b1 = (const float*)d_in[3];  // [64]
    const float* W2 = (const float*)d_in[4];  // [64]
    const float* b2 = (const float*)d_in[5];  // [1]
    int N = in_sizes[1];                      // 2048

    float* out = (float*)d_out;
    int NB = N / 32;
    int nblk = NB * (NB + 1) / 2;             // 2080 for N=2048
    gd_fused<<<nblk, 64, 0, stream>>>(z, s, W1, b1, W2, b2, out, N, NB);
}

// Round 11
// 35.706 us; speedup vs baseline: 1.1447x; 1.1447x over previous
//
#include <hip/hip_runtime.h>
#include <math.h>

#define TWO_PI_F 6.28318530717958647692f

typedef unsigned int u32;
typedef __attribute__((ext_vector_type(4))) u32      u32x4;
typedef __attribute__((ext_vector_type(4))) float    f4;
typedef __attribute__((ext_vector_type(2))) float    f2;
typedef __attribute__((ext_vector_type(2))) _Float16 h2;

union V8 { u32x4 v; h2 h[4]; };

#if __has_builtin(__builtin_amdgcn_fdot2)
#define FDOT2(a, b, c) __builtin_amdgcn_fdot2((a), (b), (c), false)
#else
__device__ __forceinline__ float FDOT2(h2 a, h2 b, float c) {
    return c + (float)a[0] * (float)b[0] + (float)a[1] * (float)b[1];
}
#endif

// ---------------------------------------------------------------------------
// Fused kernel: 32x32 output tile per block, upper-triangular blocks only
// (2080 blocks). 128 threads (2 waves), each thread owns a 2x4 patch.
// NEW vs r9: __launch_bounds__(128,2) lifts the VGPR cap to 256 (r10 showed
// VGPR=76 -> compiler couldn't keep a group's 12 ds_read_b128 in flight) and
// an explicit 2-deep register pipeline: group hg+1's 12 data reads issue
// BEFORE group hg's ~320-inst compute, so LDS latency (~120cyc) hides under
// compute (~640cyc). All pipeline indices compile-time (full unroll).
// ---------------------------------------------------------------------------
__global__ __launch_bounds__(128, 2) void gd_fused(
    const float* __restrict__ z,  const float* __restrict__ s,
    const float* __restrict__ W1, const float* __restrict__ b1,
    const float* __restrict__ W2, const float* __restrict__ b2v,
    float* __restrict__ out, int N, int NB)
{
    __shared__ __attribute__((aligned(16))) _Float16 sAB[4][32][64]; // Ai,Bi,Aj,Bj
    __shared__ __attribute__((aligned(16))) _Float16 sWc[64], sWs[64], sW2[64];
    __shared__ __attribute__((aligned(16))) f4 strig2[64]; // {c1,s1,c2,s2}; 0:31=i, 32:63=j
    __shared__ float zc[64];

    // --- triangular block decode: u -> (bi, bj), bj >= bi ---
    int u = blockIdx.x;
    int M = 2 * NB + 1;
    float disc = (float)(M * M - 8 * u);
    int bi = (int)(((float)M - sqrtf(disc)) * 0.5f);
    if (bi < 0) bi = 0;
    if (bi > NB - 1) bi = NB - 1;
    while (bi > 0 && bi * (M - bi) / 2 > u) --bi;
    while ((bi + 1) * (M - (bi + 1)) / 2 <= u) ++bi;
    int bj = bi + (u - bi * (M - bi) / 2);

    int t = threadIdx.x;

    // --- setup: t<64 does trig(row t) + zc[t]; t>=64 stages weights ---
    if (t < 64) {
        int grow = (t < 32) ? (bi * 32 + t) : (bj * 32 + (t - 32));
        float ang = TWO_PI_F * s[grow];
        float c1 = __cosf(ang);
        float s1 = __sinf(ang);
        strig2[t] = (f4){c1, s1, c1 * c1 - s1 * s1, 2.0f * c1 * s1};
        float acc = b1[t];
#pragma unroll
        for (int zz = 0; zz < 32; ++zz)
            acc = fmaf(z[zz], W1[(10 + zz) * 64 + t], acc);
        zc[t] = acc;
    } else {
        int h = t - 64;
        sWc[h] = (_Float16)W1[8 * 64 + h];
        sWs[h] = (_Float16)W1[9 * 64 + h];
        sW2[h] = (_Float16)(0.5f * W2[h]);   // fold 0.5 symmetrization
    }
    __syncthreads();

    // --- phase 1: generate A/B pairs (2 h per thread, 16 rows each) ---
    {
        int q  = t & 31;          // h-pair index: h = 2q, 2q+1
        int rg = t >> 5;          // 4 row-groups x 16 rows
        const f2* W1p = (const f2*)W1;
        f2 wv[8];
#pragma unroll
        for (int w = 0; w < 8; ++w) wv[w] = W1p[w * 32 + q];
        f2 zv = *(const f2*)&zc[2 * q];
#pragma unroll
        for (int rr = 0; rr < 16; ++rr) {
            int row = rg * 16 + rr;           // 0..63
            f4 tg = strig2[row];
            float A0 = zv.x, A1 = zv.y;
            A0 = fmaf(tg.x, wv[0].x, A0); A1 = fmaf(tg.x, wv[0].y, A1);
            A0 = fmaf(tg.y, wv[1].x, A0); A1 = fmaf(tg.y, wv[1].y, A1);
            A0 = fmaf(tg.z, wv[2].x, A0); A1 = fmaf(tg.z, wv[2].y, A1);
            A0 = fmaf(tg.w, wv[3].x, A0); A1 = fmaf(tg.w, wv[3].y, A1);
            float B0 = tg.x * wv[4].x, B1 = tg.x * wv[4].y;
            B0 = fmaf(tg.y, wv[5].x, B0); B1 = fmaf(tg.y, wv[5].y, B1);
            B0 = fmaf(tg.z, wv[6].x, B0); B1 = fmaf(tg.z, wv[6].y, B1);
            B0 = fmaf(tg.w, wv[7].x, B0); B1 = fmaf(tg.w, wv[7].y, B1);
            int arr = (row >> 5) * 2;         // 0: i-rows, 2: j-rows
            int lr  = row & 31;
            int colq = q ^ (((lr >> 2) & 7) << 2);   // pair-unit swizzle
            h2 Aw = {(_Float16)A0, (_Float16)A1};
            h2 Bw = {(_Float16)B0, (_Float16)B1};
            *(h2*)&sAB[arr + 0][lr][2 * colq] = Aw;
            *(h2*)&sAB[arr + 1][lr][2 * colq] = Bw;
        }
    }
    __syncthreads();

    // --- phase 2: 2x4 patch per thread, 2-deep register pipeline ---
    int tj = t & 7;     // col quad: jl = tj*4 + c
    int ti = t >> 3;    // row pair: il = ti*2 + r

    const int RK = ((ti >> 1) & 7) << 3;   // row swizzle key (same both rows)
    const int CK = (tj & 7) << 3;          // col swizzle key (same all 4 cols)

    h2 ct2[2][4], st2[2][4];
#pragma unroll
    for (int r = 0; r < 2; ++r) {
        int il = ti * 2 + r;
        f4 tgi = strig2[il];
#pragma unroll
        for (int c = 0; c < 4; ++c) {
            int jl = tj * 4 + c;
            f4 tgj = strig2[32 + jl];
            float cv = fmaf(tgi.x, tgj.x, tgi.y * tgj.y);            // cos(2pi*dist)
            float sv = fabsf(fmaf(tgi.y, tgj.x, -(tgi.x * tgj.y)));  // sin(2pi*dist)
            _Float16 cth = (_Float16)cv;
            _Float16 sth = (_Float16)sv;
            ct2[r][c] = (h2){cth, cth};
            st2[r][c] = (h2){sth, sth};
        }
    }

    float acc[2][4];
#pragma unroll
    for (int r = 0; r < 2; ++r)
#pragma unroll
        for (int c = 0; c < 4; ++c) acc[r][c] = 0.0f;

    const int rbase0 = (ti * 2 + 0) * 64;
    const int rbase1 = (ti * 2 + 1) * 64;
    int cbase[4];
#pragma unroll
    for (int c = 0; c < 4; ++c) cbase[c] = (tj * 4 + c) * 64;

    const _Float16* pAi = &sAB[0][0][0];
    const _Float16* pBi = &sAB[1][0][0];
    const _Float16* pAj = &sAB[2][0][0];
    const _Float16* pBj = &sAB[3][0][0];

    V8 ai8[2][2], bi8[2][2], aj8[2][4], bj8[2][4];   // [slot][r/c]

#define LOADG(S, HG) do {                                            \
        const int _h0 = (HG) * 8;                                    \
        const int _oR = _h0 ^ RK;                                    \
        const int _oC = _h0 ^ CK;                                    \
        ai8[S][0].v = *(const u32x4*)&pAi[rbase0 + _oR];             \
        ai8[S][1].v = *(const u32x4*)&pAi[rbase1 + _oR];             \
        bi8[S][0].v = *(const u32x4*)&pBi[rbase0 + _oR];             \
        bi8[S][1].v = *(const u32x4*)&pBi[rbase1 + _oR];             \
        aj8[S][0].v = *(const u32x4*)&pAj[cbase[0] + _oC];           \
        aj8[S][1].v = *(const u32x4*)&pAj[cbase[1] + _oC];           \
        aj8[S][2].v = *(const u32x4*)&pAj[cbase[2] + _oC];           \
        aj8[S][3].v = *(const u32x4*)&pAj[cbase[3] + _oC];           \
        bj8[S][0].v = *(const u32x4*)&pBj[cbase[0] + _oC];           \
        bj8[S][1].v = *(const u32x4*)&pBj[cbase[1] + _oC];           \
        bj8[S][2].v = *(const u32x4*)&pBj[cbase[2] + _oC];           \
        bj8[S][3].v = *(const u32x4*)&pBj[cbase[3] + _oC];           \
    } while (0)

    LOADG(0, 0);   // prologue: fill slot 0

#pragma unroll
    for (int hg = 0; hg < 8; ++hg) {
        const int cur = hg & 1;        // compile-time under full unroll
        const int nxt = cur ^ 1;
        if (hg < 7) LOADG(nxt, hg + 1);   // issue next group's 12 reads early

        const int h0 = hg * 8;
        V8 wc8, ws8, w28;               // uniform addr -> broadcast reads
        wc8.v = *(const u32x4*)&sWc[h0];
        ws8.v = *(const u32x4*)&sWs[h0];
        w28.v = *(const u32x4*)&sW2[h0];

#pragma unroll
        for (int r = 0; r < 2; ++r) {
#pragma unroll
            for (int c = 0; c < 4; ++c) {
                h2 ct = ct2[r][c];
                h2 st = st2[r][c];
#pragma unroll
                for (int k = 0; k < 4; ++k) {
                    h2 d2 = __builtin_elementwise_fma(ct, wc8.h[k], st * ws8.h[k]);
                    h2 p1 = ai8[cur][r].h[k] + bj8[cur][c].h[k] + d2;   // (i,j)
                    h2 p2 = aj8[cur][c].h[k] + bi8[cur][r].h[k] + d2;   // (j,i)
                    h2 m  = __builtin_elementwise_max(p1, (h2)0) +
                            __builtin_elementwise_max(p2, (h2)0);
                    acc[r][c] = FDOT2(m, w28.h[k], acc[r][c]);
                }
            }
        }
    }
#undef LOADG

    float b2 = b2v[0];
    float vals[2][4];
#pragma unroll
    for (int r = 0; r < 2; ++r) {
        int gi = bi * 32 + ti * 2 + r;
#pragma unroll
        for (int c = 0; c < 4; ++c) {
            int gj = bj * 32 + tj * 4 + c;
            float v = acc[r][c] + b2;
            if (gi == gj) v = -1e9f;
            vals[r][c] = v;
        }
    }

    // direct (upper) tile: one float4 store per row
#pragma unroll
    for (int r = 0; r < 2; ++r) {
        int gi = bi * 32 + ti * 2 + r;
        f4 o = {vals[r][0], vals[r][1], vals[r][2], vals[r][3]};
        *(f4*)&out[(size_t)gi * N + bj * 32 + tj * 4] = o;
    }

    if (bj > bi) {   // mirrored block via LDS transpose (stride 33)
        __syncthreads();
        float* tile = (float*)&sAB[0][0][0];   // 32*33*4 = 4.2 KB inside sAB
#pragma unroll
        for (int r = 0; r < 2; ++r)
#pragma unroll
            for (int c = 0; c < 4; ++c)
                tile[(ti * 2 + r) * 33 + tj * 4 + c] = vals[r][c];
        __syncthreads();
#pragma unroll
        for (int r = 0; r < 2; ++r) {
            int orow = ti * 2 + r;             // j-space row
            f4 m;
#pragma unroll
            for (int c = 0; c < 4; ++c)
                m[c] = tile[(tj * 4 + c) * 33 + orow];
            *(f4*)&out[(size_t)(bj * 32 + orow) * N + bi * 32 + tj * 4] = m;
        }
    }
}

extern "C" void kernel_launch(void* const* d_in, const int* in_sizes, int n_in,
                              void* d_out, int out_size, void* d_ws, size_t ws_size,
                              hipStream_t stream) {
    const float* z  = (const float*)d_in[0];  // [32]
    const float* s  = (const float*)d_in[1];  // [N]
    const float* W1 = (const float*)d_in[2];  // [42,64]
    const float* b1 = (const float*)d_in[3];  // [64]
    const float* W2 = (const float*)d_in[4];  // [64]
    const float* b2 = (const float*)d_in[5];  // [1]
    int N = in_sizes[1];                      // 2048

    float* out = (float*)d_out;
    int NB = N / 32;
    int nblk = NB * (NB + 1) / 2;             // 2080 for N=2048
    gd_fused<<<nblk, 128, 0, stream>>>(z, s, W1, b1, W2, b2, out, N, NB);
}